// Round 1
// 674.386 us; speedup vs baseline: 1.3559x; 1.3559x over previous
//
#include <hip/hip_runtime.h>
#include <hip/hip_bf16.h>
#include <hip/hip_fp16.h>
#include <math.h>

#define DMODEL 128
#define NHEAD 8
#define HEADD 16
#define NLAYER 2
#define FFDIM 512
#define MPAD 50048      // N rounded up to 128
#define QKVW 384        // fused qkv row width in ushorts: [q 0..127 | kv interleaved 128..383]

using short8 = __attribute__((ext_vector_type(8))) short;
using f32x4  = __attribute__((ext_vector_type(4))) float;

static __device__ __forceinline__ unsigned short f2bf(float f) {
    __hip_bfloat16 h = __float2bfloat16(f);   // RNE
    return *(unsigned short*)&h;
}
static __device__ __forceinline__ float bf2f(unsigned short u) {
    unsigned int v = ((unsigned int)u) << 16;
    return *(float*)&v;
}
static __device__ __forceinline__ unsigned short f2h(float f) {
    __half h = __float2half(f);               // RNE
    unsigned short u; __builtin_memcpy(&u, &h, 2); return u;
}
static __device__ __forceinline__ float h2f(unsigned short u) {
    __half h; __builtin_memcpy(&h, &u, 2); return __half2float(h);
}

// ---------------------------------------------------------------------------
// LayerNorm: one wave per row of 128; float2 per lane; bf16 output.
// ---------------------------------------------------------------------------
__global__ __launch_bounds__(256)
void ln_kernel(const float* __restrict__ x, const float* __restrict__ g,
               const float* __restrict__ b, unsigned short* __restrict__ out, int n)
{
    int wave = threadIdx.x >> 6;
    int lane = threadIdx.x & 63;
    int row  = blockIdx.x * 4 + wave;
    if (row >= n) return;
    float2 xv = *(const float2*)(x + (size_t)row * DMODEL + lane * 2);
    float s  = xv.x + xv.y;
    float ss = xv.x * xv.x + xv.y * xv.y;
    #pragma unroll
    for (int d = 1; d < 64; d <<= 1) {
        s  += __shfl_xor(s, d);
        ss += __shfl_xor(ss, d);
    }
    float mu   = s * (1.0f / 128.0f);
    float var  = ss * (1.0f / 128.0f) - mu * mu;
    float rstd = rsqrtf(var + 1e-5f);
    float2 gv = *(const float2*)(g + lane * 2);
    float2 bv = *(const float2*)(b + lane * 2);
    ushort2 o;
    o.x = f2bf((xv.x - mu) * rstd * gv.x + bv.x);
    o.y = f2bf((xv.y - mu) * rstd * gv.y + bv.y);
    *(ushort2*)(out + (size_t)row * DMODEL + lane * 2) = o;
}

// ---------------------------------------------------------------------------
// Weight convert + transpose: W[L][K][N] fp32 -> Wt[L][NR][K] bf16 at row
// offset rowOff (lets Wq/Wk/Wv concatenate into one [L][384][128] buffer).
// ---------------------------------------------------------------------------
__global__ void wconv(const float* __restrict__ W, unsigned short* __restrict__ Wt,
                      int K, int N, int total, int NR, int rowOff)
{
    int i = blockIdx.x * 256 + threadIdx.x;
    if (i >= total) return;
    int kn = K * N;
    int l = i / kn;
    int r = i - l * kn;
    int k = r / N;
    int nn = r - k * N;
    Wt[(size_t)l * NR * K + (size_t)(rowOff + nn) * K + k] = f2bf(W[i]);
}

// ---------------------------------------------------------------------------
// bf16 MFMA GEMM: C = A[MxK] @ B[KxN] + bias, epilogue per MODE:
//   1: out fp32 = acc + bias + Rf                (residual adds: Wo, FFN2)
//   2: out bf16 = gelu(acc + bias)               (FFN1)
//   3: out bf16 = acc + bias + Rb + degs[i]*wdeg[j] + bdeg[j]   (pos enc)
//   4: fused QKV -> fp16: q at [row][col], k/v interleaved at [row][128+...]
// A: bf16 [M x K] row-major (rows padded to 128). Bt: bf16 [N x K] (transposed).
// Block: 256 thr = 4 waves (2x2), tile 128x128, BK=32, wave does 4x4 16x16x32.
// ---------------------------------------------------------------------------
template<int MODE>
__global__ __launch_bounds__(256)
void mfma_gemm(const unsigned short* __restrict__ A, const unsigned short* __restrict__ Bt,
               const float* __restrict__ bias, const float* __restrict__ bias2,
               const float* __restrict__ bias3,
               const float* __restrict__ Rf, const unsigned short* __restrict__ Rb,
               const float* __restrict__ degs, const float* __restrict__ wdeg,
               const float* __restrict__ bdeg,
               float* __restrict__ outf, unsigned short* __restrict__ outb,
               int M, int N, int K)
{
    __shared__ __align__(16) unsigned short As[128 * 32];
    __shared__ __align__(16) unsigned short Bs[128 * 32];
    const int tid  = threadIdx.x;
    const int wave = tid >> 6, lane = tid & 63;
    const int wr = wave >> 1, wc = wave & 1;
    const int quad = lane >> 4, l15 = lane & 15;
    const size_t br = (size_t)blockIdx.x * 128;
    const size_t bc = (size_t)blockIdx.y * 128;

    f32x4 acc[4][4] = {};

    for (int kt = 0; kt < K; kt += 32) {
        #pragma unroll
        for (int c = 0; c < 2; ++c) {
            int idx = tid + c * 256;           // 0..511
            int row = idx >> 2;                // 0..127
            int kg  = idx & 3;                 // 0..3
            *(short8*)&As[row * 32 + kg * 8] =
                *(const short8*)(A + (br + row) * (size_t)K + kt + kg * 8);
            *(short8*)&Bs[row * 32 + kg * 8] =
                *(const short8*)(Bt + (bc + row) * (size_t)K + kt + kg * 8);
        }
        __syncthreads();
        short8 af[4], bfr[4];
        #pragma unroll
        for (int i = 0; i < 4; ++i)
            af[i] = *(const short8*)&As[(wr * 64 + i * 16 + l15) * 32 + quad * 8];
        #pragma unroll
        for (int j = 0; j < 4; ++j)
            bfr[j] = *(const short8*)&Bs[(wc * 64 + j * 16 + l15) * 32 + quad * 8];
        #pragma unroll
        for (int i = 0; i < 4; ++i)
            #pragma unroll
            for (int j = 0; j < 4; ++j)
                acc[i][j] = __builtin_amdgcn_mfma_f32_16x16x32_bf16(af[i], bfr[j], acc[i][j], 0, 0, 0);
        __syncthreads();
    }

    // epilogue: D row = quad*4 + reg, col = l15 (verified gfx950 C/D layout)
    #pragma unroll
    for (int i = 0; i < 4; ++i) {
        #pragma unroll
        for (int r = 0; r < 4; ++r) {
            size_t row = br + wr * 64 + i * 16 + quad * 4 + r;
            if (row >= (size_t)M) continue;
            #pragma unroll
            for (int j = 0; j < 4; ++j) {
                size_t col = bc + wc * 64 + j * 16 + l15;
                if (MODE == 4) {
                    int c   = (int)col & 127;
                    int sec = (int)(col >> 7);   // 0=q, 1=k, 2=v (uniform per block)
                    const float* bp = (sec == 0) ? bias : (sec == 1 ? bias2 : bias3);
                    float val = acc[i][j][r] + bp[c];
                    int idx = (sec == 0) ? c
                            : (DMODEL + ((c >> 1) << 2) + ((sec - 1) << 1) + (c & 1));
                    outb[row * (size_t)QKVW + idx] = f2h(val);
                } else {
                    float val = acc[i][j][r] + bias[col];
                    if (MODE == 1) {
                        outf[row * N + col] = val + Rf[row * N + col];
                    } else if (MODE == 2) {
                        val = 0.5f * val * (1.0f + erff(val * 0.70710678118654752f));
                        outb[row * N + col] = f2bf(val);
                    } else if (MODE == 3) {
                        val += bf2f(Rb[row * N + col]) + degs[row] * wdeg[col] + bdeg[col];
                        outb[row * N + col] = f2bf(val);
                    }
                }
            }
        }
    }
}

// ---------------------------------------------------------------------------
// Degree pipeline
// ---------------------------------------------------------------------------
__global__ void deg_init(float* __restrict__ deg, int n)
{
    int i = blockIdx.x * 256 + threadIdx.x;
    if (i < n) deg[i] = 1.0f;     // self loop
}

__global__ void deg_count(const int* __restrict__ src, float* __restrict__ deg, int e)
{
    int i = blockIdx.x * 256 + threadIdx.x;
    if (i < e) atomicAdd(&deg[src[i]], 1.0f);
}

__global__ __launch_bounds__(256)
void deg_var(const float* __restrict__ deg, float* __restrict__ stats, float mean, int n)
{
    float acc = 0.f;
    for (int i = blockIdx.x * blockDim.x + threadIdx.x; i < n; i += gridDim.x * blockDim.x) {
        float d = deg[i] - mean;
        acc += d * d;
    }
    #pragma unroll
    for (int d = 1; d < 64; d <<= 1) acc += __shfl_xor(acc, d);
    __shared__ float wsum[4];
    int lane = threadIdx.x & 63, wv = threadIdx.x >> 6;
    if (lane == 0) wsum[wv] = acc;
    __syncthreads();
    if (threadIdx.x == 0) atomicAdd(stats, wsum[0] + wsum[1] + wsum[2] + wsum[3]);
}

__global__ void deg_norm(const float* __restrict__ deg, const float* __restrict__ stats,
                         float* __restrict__ degs, float mean, int n)
{
    int i = blockIdx.x * 256 + threadIdx.x;
    if (i >= n) return;
    float sd = sqrtf(stats[0] / (float)(n - 1));
    degs[i] = (deg[i] - mean) / (sd + 1e-6f);
}

// ---------------------------------------------------------------------------
// CSR build (grouped by dst; self loops appended)
// ---------------------------------------------------------------------------
__global__ void csr_count(const int* __restrict__ ei, int* __restrict__ counts, int e, int n)
{
    int i = blockIdx.x * 256 + threadIdx.x;
    if (i >= e + n) return;
    int d = (i < e) ? ei[e + i] : (i - e);
    atomicAdd(&counts[d], 1);
}

__global__ __launch_bounds__(256)
void scan_block(const int* __restrict__ in, int* __restrict__ out,
                int* __restrict__ sums, int n)
{
    __shared__ int buf[2][256];
    int t = threadIdx.x;
    int i = blockIdx.x * 256 + t;
    int v = (i < n) ? in[i] : 0;
    buf[0][t] = v;
    __syncthreads();
    int cur = 0;
    #pragma unroll
    for (int d = 1; d < 256; d <<= 1) {
        int val = buf[cur][t] + ((t >= d) ? buf[cur][t - d] : 0);
        buf[cur ^ 1][t] = val;
        cur ^= 1;
        __syncthreads();
    }
    if (i < n) out[i] = buf[cur][t] - v;   // exclusive
    if (t == 255 && sums) sums[blockIdx.x] = buf[cur][255];
}

__global__ void scan_add(int* __restrict__ offs, const int* __restrict__ carry, int n)
{
    int i = blockIdx.x * 256 + threadIdx.x;
    if (i < n) offs[i] += carry[blockIdx.x];
}

__global__ void csr_fill(const int* __restrict__ ei, const int* __restrict__ offs,
                         int* __restrict__ cursor, int* __restrict__ csr_src, int e, int n)
{
    int i = blockIdx.x * 256 + threadIdx.x;
    if (i >= e + n) return;
    int d, s;
    if (i < e) { s = ei[i]; d = ei[e + i]; }
    else       { s = d = i - e; }
    int pos = offs[d] + atomicAdd(&cursor[d], 1);
    csr_src[pos] = s;
}

// ---------------------------------------------------------------------------
// Attention: one wave per dst node, single pass, online softmax.
// Lane l holds dims {2l, 2l+1}; head = lane>>3 (8 lanes/head, HD=16).
// qkv rows are fp16: [q(128) | k0,k1,v0,v1 interleaved (256)] -> ONE 8B
// load per lane per edge (was two fp32 8B loads). 1-edge-ahead prefetch.
// Output aggr in bf16 (feeds Wo MFMA GEMM).
// ---------------------------------------------------------------------------
__global__ __launch_bounds__(256)
void attn_kernel(const unsigned short* __restrict__ qkv,
                 const int* __restrict__ csr_src, const int* __restrict__ offs,
                 const int* __restrict__ counts,
                 unsigned short* __restrict__ aggr, int n)
{
    int wave = threadIdx.x >> 6;
    int lane = threadIdx.x & 63;
    int node = blockIdx.x * 4 + wave;
    if (node >= n) return;

    ushort2 qu = *(const ushort2*)(qkv + (size_t)node * QKVW + lane * 2);
    float qx = h2f(qu.x), qy = h2f(qu.y);
    int beg = offs[node];
    int cnt = counts[node];

    float m = -1e30f, s = 0.f, ax = 0.f, ay = 0.f;
    int jn = csr_src[beg];                         // cnt >= 1 always (self loop)
    ushort4 kvn = *(const ushort4*)(qkv + (size_t)jn * QKVW + DMODEL + lane * 4);
    for (int t = 0; t < cnt; ++t) {
        ushort4 kvc = kvn;
        if (t + 1 < cnt) {                         // wave-uniform branch
            jn = csr_src[beg + t + 1];
            kvn = *(const ushort4*)(qkv + (size_t)jn * QKVW + DMODEL + lane * 4);
        }
        float p = qx * h2f(kvc.x) + qy * h2f(kvc.y);
        p += __shfl_xor(p, 1);
        p += __shfl_xor(p, 2);
        p += __shfl_xor(p, 4);
        float att = p * 0.25f;                     // / sqrt(16)
        att = (att != att) ? 0.0f : fminf(fmaxf(att, -50.f), 50.f);
        float nm    = fmaxf(m, att);
        float scale = __expf(m - nm);              // 0 on first iter
        float ex    = __expf(att - nm);
        s  = s  * scale + ex;
        ax = ax * scale + ex * h2f(kvc.z);
        ay = ay * scale + ex * h2f(kvc.w);
        m = nm;
    }
    float r = 1.0f / (s + 1e-16f);
    ushort2 o;
    o.x = f2bf(ax * r);
    o.y = f2bf(ay * r);
    *(ushort2*)(aggr + (size_t)node * DMODEL + lane * 2) = o;
}

// ---------------------------------------------------------------------------
extern "C" void kernel_launch(void* const* d_in, const int* in_sizes, int n_in,
                              void* d_out, int out_size, void* d_ws, size_t ws_size,
                              hipStream_t stream)
{
    const float* x_in  = (const float*)d_in[0];
    const int*   ei    = (const int*)d_in[1];
    const float* Wq    = (const float*)d_in[2];
    const float* Wk    = (const float*)d_in[3];
    const float* Wv    = (const float*)d_in[4];
    const float* Wo    = (const float*)d_in[5];
    const float* Wpos  = (const float*)d_in[6];
    const float* Wdeg  = (const float*)d_in[7];
    const float* W1    = (const float*)d_in[8];
    const float* W2    = (const float*)d_in[9];
    const float* bq    = (const float*)d_in[10];
    const float* bk    = (const float*)d_in[11];
    const float* bv    = (const float*)d_in[12];
    const float* bo    = (const float*)d_in[13];
    const float* bpos  = (const float*)d_in[14];
    const float* bdeg  = (const float*)d_in[15];
    const float* ln1_b = (const float*)d_in[16];
    const float* ln2_b = (const float*)d_in[17];
    const float* b1    = (const float*)d_in[18];
    const float* b2    = (const float*)d_in[19];
    const float* ln1_g = (const float*)d_in[20];
    const float* ln2_g = (const float*)d_in[21];

    const int n   = in_sizes[0] / DMODEL;   // 50000
    const int e   = in_sizes[1] / 2;        // 500000
    const int tot = e + n;

    float* x = (float*)d_out;               // running node features (fp32)

    // ---- workspace layout (256B-aligned slices) ----
    char* p = (char*)d_ws;
    auto alloc = [&](size_t bytes) -> void* {
        void* r = (void*)p;
        p += (bytes + 255) & ~(size_t)255;
        return r;
    };
    float* deg     = (float*)alloc((size_t)n * 4);
    float* degs    = (float*)alloc((size_t)n * 4);
    float* stats   = (float*)alloc(256);
    int*   counts  = (int*)alloc((size_t)n * 4);
    int*   offs    = (int*)alloc((size_t)n * 4);
    int*   cursor  = (int*)alloc((size_t)n * 4);
    int*   bsums   = (int*)alloc(1024);
    int*   carry   = (int*)alloc(1024);
    int*   csr_src = (int*)alloc((size_t)tot * 4);
    unsigned short* xnb  = (unsigned short*)alloc((size_t)MPAD * DMODEL * 2);
    unsigned short* xp   = (unsigned short*)alloc((size_t)MPAD * DMODEL * 2);
    unsigned short* aggr = (unsigned short*)alloc((size_t)MPAD * DMODEL * 2);
    unsigned short* qkv  = (unsigned short*)alloc((size_t)MPAD * QKVW * 2);   // fp16
    unsigned short* hb   = (unsigned short*)alloc((size_t)MPAD * FFDIM * 2);  // full-size (no chunking)
    unsigned short* wqkvt = (unsigned short*)alloc((size_t)NLAYER * QKVW * DMODEL * 2);
    unsigned short* wot  = (unsigned short*)alloc((size_t)NLAYER * DMODEL * DMODEL * 2);
    unsigned short* wpt  = (unsigned short*)alloc((size_t)NLAYER * DMODEL * DMODEL * 2);
    unsigned short* w1t  = (unsigned short*)alloc((size_t)NLAYER * DMODEL * FFDIM * 2);
    unsigned short* w2t  = (unsigned short*)alloc((size_t)NLAYER * FFDIM * DMODEL * 2);

    const int nb_n = (n + 255) / 256;
    const int nb_e = (e + 255) / 256;
    const int nb_t = (tot + 255) / 256;
    const int nscan = nb_n;

    // ---- init ----
    hipMemcpyAsync(x, x_in, (size_t)n * DMODEL * 4, hipMemcpyDeviceToDevice, stream);
    hipMemsetAsync(stats, 0, 256, stream);
    hipMemsetAsync(counts, 0, (size_t)n * 4, stream);
    hipMemsetAsync(cursor, 0, (size_t)n * 4, stream);

    // ---- weight convert+transpose (bf16 [NR][K]); Wq/Wk/Wv concat to [384][128]
    {
        int tDD = NLAYER * DMODEL * DMODEL;
        int tW1 = NLAYER * DMODEL * FFDIM;
        wconv<<<(tDD + 255) / 256, 256, 0, stream>>>(Wq,   wqkvt, DMODEL, DMODEL, tDD, QKVW, 0);
        wconv<<<(tDD + 255) / 256, 256, 0, stream>>>(Wk,   wqkvt, DMODEL, DMODEL, tDD, QKVW, 128);
        wconv<<<(tDD + 255) / 256, 256, 0, stream>>>(Wv,   wqkvt, DMODEL, DMODEL, tDD, QKVW, 256);
        wconv<<<(tDD + 255) / 256, 256, 0, stream>>>(Wo,   wot, DMODEL, DMODEL, tDD, DMODEL, 0);
        wconv<<<(tDD + 255) / 256, 256, 0, stream>>>(Wpos, wpt, DMODEL, DMODEL, tDD, DMODEL, 0);
        wconv<<<(tW1 + 255) / 256, 256, 0, stream>>>(W1,   w1t, DMODEL, FFDIM,  tW1, FFDIM, 0);
        wconv<<<(tW1 + 255) / 256, 256, 0, stream>>>(W2,   w2t, FFDIM,  DMODEL, tW1, DMODEL, 0);
    }

    // ---- degree (layer-invariant) ----
    const float mean = (float)((double)tot / (double)n);
    deg_init<<<nb_n, 256, 0, stream>>>(deg, n);
    deg_count<<<nb_e, 256, 0, stream>>>(ei, deg, e);
    deg_var<<<196, 256, 0, stream>>>(deg, stats, mean, n);
    deg_norm<<<nb_n, 256, 0, stream>>>(deg, stats, degs, mean, n);

    // ---- CSR by dst (layer-invariant) ----
    csr_count<<<nb_t, 256, 0, stream>>>(ei, counts, e, n);
    scan_block<<<nscan, 256, 0, stream>>>(counts, offs, bsums, n);
    scan_block<<<1, 256, 0, stream>>>(bsums, carry, nullptr, nscan);
    scan_add<<<nscan, 256, 0, stream>>>(offs, carry, n);
    csr_fill<<<nb_t, 256, 0, stream>>>(ei, offs, cursor, csr_src, e, n);

    const dim3 gD((n + 127) / 128, 1);       // N=128 GEMMs over all nodes
    const dim3 gQ((n + 127) / 128, 3);       // fused QKV (N=384)
    const dim3 gF1((n + 127) / 128, 4);      // FFN1 (N=512)
    const int ln_grid = (n + 3) / 4;

    for (int l = 0; l < NLAYER; ++l) {
        const size_t DD = (size_t)DMODEL * DMODEL;
        const float* wdeg = Wdeg + (size_t)l * DMODEL;
        const unsigned short* wqkv = wqkvt + (size_t)l * QKVW * DMODEL;
        const unsigned short* wo   = wot + l * DD;
        const unsigned short* wpos = wpt + l * DD;
        const unsigned short* w1   = w1t + (size_t)l * DMODEL * FFDIM;
        const unsigned short* w2   = w2t + (size_t)l * FFDIM * DMODEL;

        // pre-attention LN -> bf16
        ln_kernel<<<ln_grid, 256, 0, stream>>>(x, ln1_g + l * DMODEL, ln1_b + l * DMODEL, xnb, n);
        // xp = xn + xn@Wpos + bpos + degs*wdeg + bdeg   (bf16 out)
        mfma_gemm<3><<<gD, 256, 0, stream>>>(xnb, wpos, bpos + l * DMODEL, nullptr, nullptr,
                                             nullptr, xnb, degs, wdeg, bdeg + l * DMODEL,
                                             nullptr, xp, n, DMODEL, DMODEL);
        // fused QKV -> fp16 qkv buffer (q | interleaved kv)
        mfma_gemm<4><<<gQ, 256, 0, stream>>>(xp, wqkv, bq + l * DMODEL, bk + l * DMODEL,
                                             bv + l * DMODEL,
                                             nullptr, nullptr, nullptr, nullptr, nullptr,
                                             nullptr, qkv, n, QKVW, DMODEL);
        // attention -> aggr (bf16)
        attn_kernel<<<ln_grid, 256, 0, stream>>>(qkv, csr_src, offs, counts, aggr, n);
        // x = x + aggr@Wo + bo   (fp32)
        mfma_gemm<1><<<gD, 256, 0, stream>>>(aggr, wo, bo + l * DMODEL, nullptr, nullptr,
                                             x, nullptr, nullptr, nullptr, nullptr,
                                             x, nullptr, n, DMODEL, DMODEL);
        // FFN (un-chunked: full-size hb)
        ln_kernel<<<ln_grid, 256, 0, stream>>>(x, ln2_g + l * DMODEL, ln2_b + l * DMODEL, xnb, n);
        mfma_gemm<2><<<gF1, 256, 0, stream>>>(xnb, w1, b1 + l * FFDIM, nullptr, nullptr,
                                              nullptr, nullptr, nullptr, nullptr, nullptr,
                                              nullptr, hb, n, FFDIM, DMODEL);
        mfma_gemm<1><<<gD, 256, 0, stream>>>(hb, w2, b2 + l * DMODEL, nullptr, nullptr,
                                             x, nullptr, nullptr, nullptr, nullptr,
                                             x, nullptr, n, DMODEL, FFDIM);
    }
}

// Round 4
// 651.899 us; speedup vs baseline: 1.4027x; 1.0345x over previous
//
#include <hip/hip_runtime.h>
#include <hip/hip_bf16.h>
#include <hip/hip_fp16.h>
#include <math.h>

#define DMODEL 128
#define NHEAD 8
#define HEADD 16
#define NLAYER 2
#define FFDIM 512
#define MPAD 50048      // N rounded up to 128
#define QKVW 384        // fused qkv row width in ushorts: [q 0..127 | kv interleaved 128..383]

using short8 = __attribute__((ext_vector_type(8))) short;
using half8  = __attribute__((ext_vector_type(8))) _Float16;
using f32x4  = __attribute__((ext_vector_type(4))) float;

static __device__ __forceinline__ unsigned short f2h(float f) {
    __half h = __float2half(f);               // RNE
    unsigned short u; __builtin_memcpy(&u, &h, 2); return u;
}
static __device__ __forceinline__ float h2f(unsigned short u) {
    __half h; __builtin_memcpy(&h, &u, 2); return __half2float(h);
}
static __device__ __forceinline__ half8 s2h8(short8 s) {
    half8 h; __builtin_memcpy(&h, &s, 16); return h;
}
static __device__ __forceinline__ f32x4 MFMAH(short8 a, short8 b, f32x4 c) {
    return __builtin_amdgcn_mfma_f32_16x16x32_f16(s2h8(a), s2h8(b), c, 0, 0, 0);
}

// ---------------------------------------------------------------------------
// LayerNorm: one wave per row of 128; float2 per lane; fp16 output.
// ---------------------------------------------------------------------------
__global__ __launch_bounds__(256)
void ln_kernel(const float* __restrict__ x, const float* __restrict__ g,
               const float* __restrict__ b, unsigned short* __restrict__ out, int n)
{
    int wave = threadIdx.x >> 6;
    int lane = threadIdx.x & 63;
    int row  = blockIdx.x * 4 + wave;
    if (row >= n) return;
    float2 xv = *(const float2*)(x + (size_t)row * DMODEL + lane * 2);
    float s  = xv.x + xv.y;
    float ss = xv.x * xv.x + xv.y * xv.y;
    #pragma unroll
    for (int d = 1; d < 64; d <<= 1) {
        s  += __shfl_xor(s, d);
        ss += __shfl_xor(ss, d);
    }
    float mu   = s * (1.0f / 128.0f);
    float var  = ss * (1.0f / 128.0f) - mu * mu;
    float rstd = rsqrtf(var + 1e-5f);
    float2 gv = *(const float2*)(g + lane * 2);
    float2 bv = *(const float2*)(b + lane * 2);
    ushort2 o;
    o.x = f2h((xv.x - mu) * rstd * gv.x + bv.x);
    o.y = f2h((xv.y - mu) * rstd * gv.y + bv.y);
    *(ushort2*)(out + (size_t)row * DMODEL + lane * 2) = o;
}

// ---------------------------------------------------------------------------
// Weight convert + transpose: W[L][K][N] fp32 -> Wt[L][NR][K] fp16 at row
// offset rowOff (lets Wq/Wk/Wv concatenate into one [L][384][128] buffer).
// ---------------------------------------------------------------------------
__global__ void wconv(const float* __restrict__ W, unsigned short* __restrict__ Wt,
                      int K, int N, int total, int NR, int rowOff)
{
    int i = blockIdx.x * 256 + threadIdx.x;
    if (i >= total) return;
    int kn = K * N;
    int l = i / kn;
    int r = i - l * kn;
    int k = r / N;
    int nn = r - k * N;
    Wt[(size_t)l * NR * K + (size_t)(rowOff + nn) * K + k] = f2h(W[i]);
}

// ---------------------------------------------------------------------------
// fp16 MFMA GEMM: C = A[MxK] @ B[KxN] + bias, epilogue per MODE:
//   1: out fp32 = acc + bias + Rf                (residual adds: Wo, FFN2)
//   2: out fp16 = gelu(acc + bias)               (FFN1)
//   3: out fp16 = acc + bias + Rb + degs[i]*wdeg[j] + bdeg[j]   (pos enc)
//   4: fused QKV -> fp16: q at [row][col], k/v interleaved at [row][128+...]
// A: fp16 [M x K] row-major (rows padded to 128). Bt: fp16 [N x K] (transposed).
// Block: 256 thr = 4 waves (2x2), tile 128x128, BK=32, wave does 4x4 16x16x32.
// ---------------------------------------------------------------------------
template<int MODE>
__global__ __launch_bounds__(256)
void mfma_gemm(const unsigned short* __restrict__ A, const unsigned short* __restrict__ Bt,
               const float* __restrict__ bias, const float* __restrict__ bias2,
               const float* __restrict__ bias3,
               const float* __restrict__ Rf, const unsigned short* __restrict__ Rb,
               const float* __restrict__ degs, const float* __restrict__ wdeg,
               const float* __restrict__ bdeg,
               float* __restrict__ outf, unsigned short* __restrict__ outb,
               int M, int N, int K)
{
    __shared__ __align__(16) unsigned short As[128 * 32];
    __shared__ __align__(16) unsigned short Bs[128 * 32];
    const int tid  = threadIdx.x;
    const int wave = tid >> 6, lane = tid & 63;
    const int wr = wave >> 1, wc = wave & 1;
    const int quad = lane >> 4, l15 = lane & 15;
    const size_t br = (size_t)blockIdx.x * 128;
    const size_t bc = (size_t)blockIdx.y * 128;

    f32x4 acc[4][4] = {};

    for (int kt = 0; kt < K; kt += 32) {
        #pragma unroll
        for (int c = 0; c < 2; ++c) {
            int idx = tid + c * 256;           // 0..511
            int row = idx >> 2;                // 0..127
            int kg  = idx & 3;                 // 0..3
            *(short8*)&As[row * 32 + kg * 8] =
                *(const short8*)(A + (br + row) * (size_t)K + kt + kg * 8);
            *(short8*)&Bs[row * 32 + kg * 8] =
                *(const short8*)(Bt + (bc + row) * (size_t)K + kt + kg * 8);
        }
        __syncthreads();
        short8 af[4], bfr[4];
        #pragma unroll
        for (int i = 0; i < 4; ++i)
            af[i] = *(const short8*)&As[(wr * 64 + i * 16 + l15) * 32 + quad * 8];
        #pragma unroll
        for (int j = 0; j < 4; ++j)
            bfr[j] = *(const short8*)&Bs[(wc * 64 + j * 16 + l15) * 32 + quad * 8];
        #pragma unroll
        for (int i = 0; i < 4; ++i)
            #pragma unroll
            for (int j = 0; j < 4; ++j)
                acc[i][j] = MFMAH(af[i], bfr[j], acc[i][j]);
        __syncthreads();
    }

    // epilogue: D row = quad*4 + reg, col = l15 (verified gfx950 C/D layout)
    #pragma unroll
    for (int i = 0; i < 4; ++i) {
        #pragma unroll
        for (int r = 0; r < 4; ++r) {
            size_t row = br + wr * 64 + i * 16 + quad * 4 + r;
            if (row >= (size_t)M) continue;
            #pragma unroll
            for (int j = 0; j < 4; ++j) {
                size_t col = bc + wc * 64 + j * 16 + l15;
                if (MODE == 4) {
                    int c   = (int)col & 127;
                    int sec = (int)(col >> 7);   // 0=q, 1=k, 2=v (uniform per block)
                    const float* bp = (sec == 0) ? bias : (sec == 1 ? bias2 : bias3);
                    float val = acc[i][j][r] + bp[c];
                    int idx = (sec == 0) ? c
                            : (DMODEL + ((c >> 1) << 2) + ((sec - 1) << 1) + (c & 1));
                    outb[row * (size_t)QKVW + idx] = f2h(val);
                } else {
                    float val = acc[i][j][r] + bias[col];
                    if (MODE == 1) {
                        outf[row * N + col] = val + Rf[row * N + col];
                    } else if (MODE == 2) {
                        val = 0.5f * val * (1.0f + erff(val * 0.70710678118654752f));
                        outb[row * N + col] = f2h(val);
                    } else if (MODE == 3) {
                        val += h2f(Rb[row * N + col]) + degs[row] * wdeg[col] + bdeg[col];
                        outb[row * N + col] = f2h(val);
                    }
                }
            }
        }
    }
}

// ---------------------------------------------------------------------------
// Degree pipeline
// ---------------------------------------------------------------------------
__global__ void deg_init(float* __restrict__ deg, int n)
{
    int i = blockIdx.x * 256 + threadIdx.x;
    if (i < n) deg[i] = 1.0f;     // self loop
}

__global__ void deg_count(const int* __restrict__ src, float* __restrict__ deg, int e)
{
    int i = blockIdx.x * 256 + threadIdx.x;
    if (i < e) atomicAdd(&deg[src[i]], 1.0f);
}

__global__ __launch_bounds__(256)
void deg_var(const float* __restrict__ deg, float* __restrict__ stats, float mean, int n)
{
    float acc = 0.f;
    for (int i = blockIdx.x * blockDim.x + threadIdx.x; i < n; i += gridDim.x * blockDim.x) {
        float d = deg[i] - mean;
        acc += d * d;
    }
    #pragma unroll
    for (int d = 1; d < 64; d <<= 1) acc += __shfl_xor(acc, d);
    __shared__ float wsum[4];
    int lane = threadIdx.x & 63, wv = threadIdx.x >> 6;
    if (lane == 0) wsum[wv] = acc;
    __syncthreads();
    if (threadIdx.x == 0) atomicAdd(stats, wsum[0] + wsum[1] + wsum[2] + wsum[3]);
}

__global__ void deg_norm(const float* __restrict__ deg, const float* __restrict__ stats,
                         float* __restrict__ degs, float mean, int n)
{
    int i = blockIdx.x * 256 + threadIdx.x;
    if (i >= n) return;
    float sd = sqrtf(stats[0] / (float)(n - 1));
    degs[i] = (deg[i] - mean) / (sd + 1e-6f);
}

// ---------------------------------------------------------------------------
// CSR build (grouped by dst; self loops appended)
// ---------------------------------------------------------------------------
__global__ void csr_count(const int* __restrict__ ei, int* __restrict__ counts, int e, int n)
{
    int i = blockIdx.x * 256 + threadIdx.x;
    if (i >= e + n) return;
    int d = (i < e) ? ei[e + i] : (i - e);
    atomicAdd(&counts[d], 1);
}

__global__ __launch_bounds__(256)
void scan_block(const int* __restrict__ in, int* __restrict__ out,
                int* __restrict__ sums, int n)
{
    __shared__ int buf[2][256];
    int t = threadIdx.x;
    int i = blockIdx.x * 256 + t;
    int v = (i < n) ? in[i] : 0;
    buf[0][t] = v;
    __syncthreads();
    int cur = 0;
    #pragma unroll
    for (int d = 1; d < 256; d <<= 1) {
        int val = buf[cur][t] + ((t >= d) ? buf[cur][t - d] : 0);
        buf[cur ^ 1][t] = val;
        cur ^= 1;
        __syncthreads();
    }
    if (i < n) out[i] = buf[cur][t] - v;   // exclusive
    if (t == 255 && sums) sums[blockIdx.x] = buf[cur][255];
}

__global__ void scan_add(int* __restrict__ offs, const int* __restrict__ carry, int n)
{
    int i = blockIdx.x * 256 + threadIdx.x;
    if (i < n) offs[i] += carry[blockIdx.x];
}

__global__ void csr_fill(const int* __restrict__ ei, const int* __restrict__ offs,
                         int* __restrict__ cursor, int* __restrict__ csr_src, int e, int n)
{
    int i = blockIdx.x * 256 + threadIdx.x;
    if (i >= e + n) return;
    int d, s;
    if (i < e) { s = ei[i]; d = ei[e + i]; }
    else       { s = d = i - e; }
    int pos = offs[d] + atomicAdd(&cursor[d], 1);
    csr_src[pos] = s;
}

// ---------------------------------------------------------------------------
// Attention: one wave per dst node, online softmax, 2-edge unroll with
// 2-deep prefetch. Lane l holds dims {2l, 2l+1}; head = lane>>3.
// qkv rows fp16: [q(128) | k0,k1,v0,v1 interleaved (256)]. aggr out fp16.
// ---------------------------------------------------------------------------
__global__ __launch_bounds__(256)
void attn_kernel(const unsigned short* __restrict__ qkv,
                 const int* __restrict__ csr_src, const int* __restrict__ offs,
                 const int* __restrict__ counts,
                 unsigned short* __restrict__ aggr, int n)
{
    int wave = threadIdx.x >> 6;
    int lane = threadIdx.x & 63;
    int node = blockIdx.x * 4 + wave;
    if (node >= n) return;

    ushort2 qu = *(const ushort2*)(qkv + (size_t)node * QKVW + lane * 2);
    float qx = h2f(qu.x), qy = h2f(qu.y);
    int beg = offs[node], cnt = counts[node];

    float m = -1e30f, s = 0.f, ax = 0.f, ay = 0.f;
    ushort4 kvA = {0,0,0,0}, kvB = {0,0,0,0};
    if (cnt > 1) {
        int j0 = csr_src[beg], j1 = csr_src[beg + 1];
        kvA = *(const ushort4*)(qkv + (size_t)j0 * QKVW + DMODEL + lane * 4);
        kvB = *(const ushort4*)(qkv + (size_t)j1 * QKVW + DMODEL + lane * 4);
    } else {
        int j0 = csr_src[beg];
        kvA = *(const ushort4*)(qkv + (size_t)j0 * QKVW + DMODEL + lane * 4);
    }
    int t = 0;
    for (; t + 1 < cnt; t += 2) {
        ushort4 k0 = kvA, k1 = kvB;
        int rem = cnt - t - 2;
        if (rem >= 2) {
            int j0 = csr_src[beg + t + 2], j1 = csr_src[beg + t + 3];
            kvA = *(const ushort4*)(qkv + (size_t)j0 * QKVW + DMODEL + lane * 4);
            kvB = *(const ushort4*)(qkv + (size_t)j1 * QKVW + DMODEL + lane * 4);
        } else if (rem == 1) {
            int j0 = csr_src[beg + t + 2];
            kvA = *(const ushort4*)(qkv + (size_t)j0 * QKVW + DMODEL + lane * 4);
        }
        float p0 = qx * h2f(k0.x) + qy * h2f(k0.y);
        float p1 = qx * h2f(k1.x) + qy * h2f(k1.y);
        p0 += __shfl_xor(p0, 1); p1 += __shfl_xor(p1, 1);
        p0 += __shfl_xor(p0, 2); p1 += __shfl_xor(p1, 2);
        p0 += __shfl_xor(p0, 4); p1 += __shfl_xor(p1, 4);
        p0 *= 0.25f; p1 *= 0.25f;
        p0 = (p0 != p0) ? 0.f : fminf(fmaxf(p0, -50.f), 50.f);
        p1 = (p1 != p1) ? 0.f : fminf(fmaxf(p1, -50.f), 50.f);
        float nm = fmaxf(m, fmaxf(p0, p1));
        float sc = __expf(m - nm);
        float e0 = __expf(p0 - nm), e1 = __expf(p1 - nm);
        s  = s  * sc + e0 + e1;
        ax = ax * sc + e0 * h2f(k0.z) + e1 * h2f(k1.z);
        ay = ay * sc + e0 * h2f(k0.w) + e1 * h2f(k1.w);
        m = nm;
    }
    if (t < cnt) {
        float p0 = qx * h2f(kvA.x) + qy * h2f(kvA.y);
        p0 += __shfl_xor(p0, 1); p0 += __shfl_xor(p0, 2); p0 += __shfl_xor(p0, 4);
        p0 *= 0.25f;
        p0 = (p0 != p0) ? 0.f : fminf(fmaxf(p0, -50.f), 50.f);
        float nm = fmaxf(m, p0);
        float sc = __expf(m - nm), e0 = __expf(p0 - nm);
        s = s * sc + e0;
        ax = ax * sc + e0 * h2f(kvA.z);
        ay = ay * sc + e0 * h2f(kvA.w);
        m = nm;
    }
    float r = 1.0f / (s + 1e-16f);
    ushort2 o;
    o.x = f2h(ax * r);
    o.y = f2h(ay * r);
    *(ushort2*)(aggr + (size_t)node * DMODEL + lane * 2) = o;
}

// ---------------------------------------------------------------------------
extern "C" void kernel_launch(void* const* d_in, const int* in_sizes, int n_in,
                              void* d_out, int out_size, void* d_ws, size_t ws_size,
                              hipStream_t stream)
{
    const float* x_in  = (const float*)d_in[0];
    const int*   ei    = (const int*)d_in[1];
    const float* Wq    = (const float*)d_in[2];
    const float* Wk    = (const float*)d_in[3];
    const float* Wv    = (const float*)d_in[4];
    const float* Wo    = (const float*)d_in[5];
    const float* Wpos  = (const float*)d_in[6];
    const float* Wdeg  = (const float*)d_in[7];
    const float* W1    = (const float*)d_in[8];
    const float* W2    = (const float*)d_in[9];
    const float* bq    = (const float*)d_in[10];
    const float* bk    = (const float*)d_in[11];
    const float* bv    = (const float*)d_in[12];
    const float* bo    = (const float*)d_in[13];
    const float* bpos  = (const float*)d_in[14];
    const float* bdeg  = (const float*)d_in[15];
    const float* ln1_b = (const float*)d_in[16];
    const float* ln2_b = (const float*)d_in[17];
    const float* b1    = (const float*)d_in[18];
    const float* b2    = (const float*)d_in[19];
    const float* ln1_g = (const float*)d_in[20];
    const float* ln2_g = (const float*)d_in[21];

    const int n   = in_sizes[0] / DMODEL;   // 50000
    const int e   = in_sizes[1] / 2;        // 500000
    const int tot = e + n;

    float* x = (float*)d_out;               // running node features (fp32)

    // ---- workspace layout (256B-aligned slices) ----
    char* p = (char*)d_ws;
    auto alloc = [&](size_t bytes) -> void* {
        void* r = (void*)p;
        p += (bytes + 255) & ~(size_t)255;
        return r;
    };
    float* deg     = (float*)alloc((size_t)n * 4);
    float* degs    = (float*)alloc((size_t)n * 4);
    float* stats   = (float*)alloc(256);
    int*   counts  = (int*)alloc((size_t)n * 4);
    int*   offs    = (int*)alloc((size_t)n * 4);
    int*   cursor  = (int*)alloc((size_t)n * 4);
    int*   bsums   = (int*)alloc(1024);
    int*   carry   = (int*)alloc(1024);
    int*   csr_src = (int*)alloc((size_t)tot * 4);
    unsigned short* xnb  = (unsigned short*)alloc((size_t)MPAD * DMODEL * 2);
    unsigned short* xp   = (unsigned short*)alloc((size_t)MPAD * DMODEL * 2);
    unsigned short* aggr = (unsigned short*)alloc((size_t)MPAD * DMODEL * 2);
    unsigned short* qkv  = (unsigned short*)alloc((size_t)MPAD * QKVW * 2);   // fp16
    unsigned short* hb   = (unsigned short*)alloc((size_t)MPAD * FFDIM * 2);  // full-size
    unsigned short* wqkvt = (unsigned short*)alloc((size_t)NLAYER * QKVW * DMODEL * 2);
    unsigned short* wot  = (unsigned short*)alloc((size_t)NLAYER * DMODEL * DMODEL * 2);
    unsigned short* wpt  = (unsigned short*)alloc((size_t)NLAYER * DMODEL * DMODEL * 2);
    unsigned short* w1t  = (unsigned short*)alloc((size_t)NLAYER * DMODEL * FFDIM * 2);
    unsigned short* w2t  = (unsigned short*)alloc((size_t)NLAYER * FFDIM * DMODEL * 2);

    const int nb_n = (n + 255) / 256;
    const int nb_e = (e + 255) / 256;
    const int nb_t = (tot + 255) / 256;
    const int nscan = nb_n;

    // ---- init ----
    hipMemcpyAsync(x, x_in, (size_t)n * DMODEL * 4, hipMemcpyDeviceToDevice, stream);
    hipMemsetAsync(stats, 0, 256, stream);
    hipMemsetAsync(counts, 0, (size_t)n * 4, stream);
    hipMemsetAsync(cursor, 0, (size_t)n * 4, stream);

    // ---- weight convert+transpose (fp16 [NR][K]); Wq/Wk/Wv concat to [384][128]
    {
        int tDD = NLAYER * DMODEL * DMODEL;
        int tW1 = NLAYER * DMODEL * FFDIM;
        wconv<<<(tDD + 255) / 256, 256, 0, stream>>>(Wq,   wqkvt, DMODEL, DMODEL, tDD, QKVW, 0);
        wconv<<<(tDD + 255) / 256, 256, 0, stream>>>(Wk,   wqkvt, DMODEL, DMODEL, tDD, QKVW, 128);
        wconv<<<(tDD + 255) / 256, 256, 0, stream>>>(Wv,   wqkvt, DMODEL, DMODEL, tDD, QKVW, 256);
        wconv<<<(tDD + 255) / 256, 256, 0, stream>>>(Wo,   wot, DMODEL, DMODEL, tDD, DMODEL, 0);
        wconv<<<(tDD + 255) / 256, 256, 0, stream>>>(Wpos, wpt, DMODEL, DMODEL, tDD, DMODEL, 0);
        wconv<<<(tW1 + 255) / 256, 256, 0, stream>>>(W1,   w1t, DMODEL, FFDIM,  tW1, FFDIM, 0);
        wconv<<<(tW1 + 255) / 256, 256, 0, stream>>>(W2,   w2t, FFDIM,  DMODEL, tW1, DMODEL, 0);
    }

    // ---- degree (layer-invariant) ----
    const float mean = (float)((double)tot / (double)n);
    deg_init<<<nb_n, 256, 0, stream>>>(deg, n);
    deg_count<<<nb_e, 256, 0, stream>>>(ei, deg, e);
    deg_var<<<196, 256, 0, stream>>>(deg, stats, mean, n);
    deg_norm<<<nb_n, 256, 0, stream>>>(deg, stats, degs, mean, n);

    // ---- CSR by dst (layer-invariant) ----
    csr_count<<<nb_t, 256, 0, stream>>>(ei, counts, e, n);
    scan_block<<<nscan, 256, 0, stream>>>(counts, offs, bsums, n);
    scan_block<<<1, 256, 0, stream>>>(bsums, carry, nullptr, nscan);
    scan_add<<<nscan, 256, 0, stream>>>(offs, carry, n);
    csr_fill<<<nb_t, 256, 0, stream>>>(ei, offs, cursor, csr_src, e, n);

    const dim3 gD((n + 127) / 128, 1);       // N=128 GEMMs over all nodes
    const dim3 gQ((n + 127) / 128, 3);       // fused QKV (N=384)
    const dim3 gF1((n + 127) / 128, 4);      // FFN1 (N=512)
    const int ln_grid = (n + 3) / 4;

    for (int l = 0; l < NLAYER; ++l) {
        const size_t DD = (size_t)DMODEL * DMODEL;
        const float* wdeg = Wdeg + (size_t)l * DMODEL;
        const unsigned short* wqkv = wqkvt + (size_t)l * QKVW * DMODEL;
        const unsigned short* wo   = wot + l * DD;
        const unsigned short* wpos = wpt + l * DD;
        const unsigned short* w1   = w1t + (size_t)l * DMODEL * FFDIM;
        const unsigned short* w2   = w2t + (size_t)l * FFDIM * DMODEL;

        // pre-attention LN -> fp16
        ln_kernel<<<ln_grid, 256, 0, stream>>>(x, ln1_g + l * DMODEL, ln1_b + l * DMODEL, xnb, n);
        // xp = xn + xn@Wpos + bpos + degs*wdeg + bdeg   (fp16 out)
        mfma_gemm<3><<<gD, 256, 0, stream>>>(xnb, wpos, bpos + l * DMODEL, nullptr, nullptr,
                                             nullptr, xnb, degs, wdeg, bdeg + l * DMODEL,
                                             nullptr, xp, n, DMODEL, DMODEL);
        // fused QKV -> fp16 qkv buffer (q | interleaved kv)
        mfma_gemm<4><<<gQ, 256, 0, stream>>>(xp, wqkv, bq + l * DMODEL, bk + l * DMODEL,
                                             bv + l * DMODEL,
                                             nullptr, nullptr, nullptr, nullptr, nullptr,
                                             nullptr, qkv, n, QKVW, DMODEL);
        // attention -> aggr (fp16)
        attn_kernel<<<ln_grid, 256, 0, stream>>>(qkv, csr_src, offs, counts, aggr, n);
        // x = x + aggr@Wo + bo   (fp32)
        mfma_gemm<1><<<gD, 256, 0, stream>>>(aggr, wo, bo + l * DMODEL, nullptr, nullptr,
                                             x, nullptr, nullptr, nullptr, nullptr,
                                             x, nullptr, n, DMODEL, DMODEL);
        // FFN
        ln_kernel<<<ln_grid, 256, 0, stream>>>(x, ln2_g + l * DMODEL, ln2_b + l * DMODEL, xnb, n);
        mfma_gemm<2><<<gF1, 256, 0, stream>>>(xnb, w1, b1 + l * FFDIM, nullptr, nullptr,
                                              nullptr, nullptr, nullptr, nullptr, nullptr,
                                              nullptr, hb, n, FFDIM, DMODEL);
        mfma_gemm<1><<<gD, 256, 0, stream>>>(hb, w2, b2 + l * DMODEL, nullptr, nullptr,
                                             x, nullptr, nullptr, nullptr, nullptr,
                                             x, nullptr, n, DMODEL, FFDIM);
    }
}

// Round 5
// 619.172 us; speedup vs baseline: 1.4768x; 1.0529x over previous
//
#include <hip/hip_runtime.h>
#include <hip/hip_bf16.h>
#include <hip/hip_fp16.h>
#include <math.h>

#define DMODEL 128
#define NHEAD 8
#define HEADD 16
#define NLAYER 2
#define FFDIM 512
#define MPAD 50048      // N rounded up to 128 (782 tiles of 64)
#define QKVW 384        // fused qkv row width in ushorts: [q 0..127 | kv interleaved 128..383]

using short8 = __attribute__((ext_vector_type(8))) short;
using half8  = __attribute__((ext_vector_type(8))) _Float16;
using f32x4  = __attribute__((ext_vector_type(4))) float;

static __device__ __forceinline__ unsigned short f2h(float f) {
    __half h = __float2half(f);               // RNE
    unsigned short u; __builtin_memcpy(&u, &h, 2); return u;
}
static __device__ __forceinline__ float h2f(unsigned short u) {
    __half h; __builtin_memcpy(&h, &u, 2); return __half2float(h);
}
static __device__ __forceinline__ half8 s2h8(short8 s) {
    half8 h; __builtin_memcpy(&h, &s, 16); return h;
}
static __device__ __forceinline__ f32x4 MFMAH(short8 a, short8 b, f32x4 c) {
    return __builtin_amdgcn_mfma_f32_16x16x32_f16(s2h8(a), s2h8(b), c, 0, 0, 0);
}
// gelu via exp-based tanh: 0.5x(1+tanh(0.79788456(x+0.044715x^3)))
// max |delta| vs exact erf-gelu ~3e-4 -- far below the 0.29 error margin.
static __device__ __forceinline__ float gelu_fast(float v) {
    float u = v * (0.7978845608f + 0.0356774081f * v * v);
    float t = 1.0f - 2.0f / (1.0f + __expf(2.0f * u));
    return 0.5f * v * (1.0f + t);
}

// ---------------------------------------------------------------------------
// LayerNorm: one wave per row of 128; float2 per lane; fp16 output.
// ---------------------------------------------------------------------------
__global__ __launch_bounds__(256)
void ln_kernel(const float* __restrict__ x, const float* __restrict__ g,
               const float* __restrict__ b, unsigned short* __restrict__ out, int n)
{
    int wave = threadIdx.x >> 6;
    int lane = threadIdx.x & 63;
    int row  = blockIdx.x * 4 + wave;
    if (row >= n) return;
    float2 xv = *(const float2*)(x + (size_t)row * DMODEL + lane * 2);
    float s  = xv.x + xv.y;
    float ss = xv.x * xv.x + xv.y * xv.y;
    #pragma unroll
    for (int d = 1; d < 64; d <<= 1) {
        s  += __shfl_xor(s, d);
        ss += __shfl_xor(ss, d);
    }
    float mu   = s * (1.0f / 128.0f);
    float var  = ss * (1.0f / 128.0f) - mu * mu;
    float rstd = rsqrtf(var + 1e-5f);
    float2 gv = *(const float2*)(g + lane * 2);
    float2 bv = *(const float2*)(b + lane * 2);
    ushort2 o;
    o.x = f2h((xv.x - mu) * rstd * gv.x + bv.x);
    o.y = f2h((xv.y - mu) * rstd * gv.y + bv.y);
    *(ushort2*)(out + (size_t)row * DMODEL + lane * 2) = o;
}

// ---------------------------------------------------------------------------
// Weight convert + transpose: W[L][K][N] fp32 -> Wt[L][NR][K] fp16 at rowOff.
// ---------------------------------------------------------------------------
__global__ void wconv(const float* __restrict__ W, unsigned short* __restrict__ Wt,
                      int K, int N, int total, int NR, int rowOff)
{
    int i = blockIdx.x * 256 + threadIdx.x;
    if (i >= total) return;
    int kn = K * N;
    int l = i / kn;
    int r = i - l * kn;
    int k = r / N;
    int nn = r - k * N;
    Wt[(size_t)l * NR * K + (size_t)(rowOff + nn) * K + k] = f2h(W[i]);
}

// ---------------------------------------------------------------------------
// B-resident fp16 MFMA GEMM.
// Block: 256 thr = 4 waves (2x2); block tile 64 rows x 128 cols.
// B panel (128 cols x 128 K) staged ONCE per K-chunk into padded LDS
// (stride 130 shorts -> <=2-way bank conflicts), fragments hoisted to regs.
// A tiles (64 x 128 K) iterated TPB per block with register prefetch of the
// next tile's global loads (latency hides under MFMA).
// KCH = K/128 chunks (1 for K=128 ops, 4 for FFN2); acc held across chunks.
// MODE epilogues:
//   0: fused QKV -> fp16 [q | kv interleaved], sec = blockIdx.y
//   1: outf[r][c] += acc + bias[c]           (Wo residual, FFN2)
//   2: outb = gelu(acc + bias)  fp16         (FFN1)
//   3: outb = acc + bias + Rb + degs[r]*wdeg[c] + bdeg[c]  fp16 (pos enc)
// K-accumulation order identical to the verified round-4 kernel.
// ---------------------------------------------------------------------------
template<int MODE, int KCH, int TPB>
__global__ __launch_bounds__(256)
void gemm_bres(const unsigned short* __restrict__ A, int strideA,
               const unsigned short* __restrict__ Bt, int strideB,
               const float* __restrict__ bias, const float* __restrict__ bias2,
               const float* __restrict__ bias3,
               const unsigned short* __restrict__ Rb,
               const float* __restrict__ degs, const float* __restrict__ wdeg,
               const float* __restrict__ bdeg,
               float* __restrict__ outf, unsigned short* __restrict__ outb,
               int outStride, int n)
{
    __shared__ __align__(16) unsigned short As[64 * 130];
    __shared__ __align__(16) unsigned short Bs[128 * 130];

    const int tid  = threadIdx.x;
    const int wave = tid >> 6, lane = tid & 63;
    const int wr = wave >> 1, wc = wave & 1;
    const int quad = lane >> 4, l15 = lane & 15;
    const int bc = blockIdx.y * 128;

    f32x4 acc[2][4] = {};
    short8 bfr[4][4];
    short8 pr[4];

    // prefetch A tile (ky=0, t=0)
    {
        const int row0 = blockIdx.x * TPB * 64;
        #pragma unroll
        for (int c = 0; c < 4; ++c) {
            int g = tid + c * 256;
            int r = g >> 4, col8 = g & 15;
            pr[c] = *(const short8*)(A + (size_t)(row0 + r) * strideA + col8 * 8);
        }
    }

    for (int ky = 0; ky < KCH; ++ky) {
        const int kOff = ky * 128;
        // stage B panel for this K-chunk
        #pragma unroll
        for (int c = 0; c < 8; ++c) {
            int g = tid + c * 256;                 // 0..2047
            int r = g >> 4, col8 = g & 15;
            *(short8*)&Bs[r * 130 + col8 * 8] =
                *(const short8*)(Bt + (size_t)(bc + r) * strideB + kOff + col8 * 8);
        }
        for (int t = 0; t < TPB; ++t) {
            // write prefetched A regs to LDS
            #pragma unroll
            for (int c = 0; c < 4; ++c) {
                int g = tid + c * 256;             // 0..1023
                int r = g >> 4, col8 = g & 15;
                *(short8*)&As[r * 130 + col8 * 8] = pr[c];
            }
            // prefetch next (ky,t) A tile
            {
                int nt = t + 1, nky = ky;
                if (nt == TPB) { nt = 0; nky = ky + 1; }
                if (nky < KCH) {
                    const int nrow0 = (blockIdx.x * TPB + nt) * 64;
                    const int nkOff = nky * 128;
                    #pragma unroll
                    for (int c = 0; c < 4; ++c) {
                        int g = tid + c * 256;
                        int r = g >> 4, col8 = g & 15;
                        pr[c] = *(const short8*)(A + (size_t)(nrow0 + r) * strideA + nkOff + col8 * 8);
                    }
                }
            }
            __syncthreads();                        // A (and B at t==0) visible
            if (t == 0) {
                #pragma unroll
                for (int j = 0; j < 4; ++j)
                    #pragma unroll
                    for (int ks = 0; ks < 4; ++ks)
                        bfr[j][ks] = *(const short8*)&Bs[(wc * 64 + j * 16 + l15) * 130 + (ks * 4 + quad) * 8];
            }
            if (KCH == 1) {
                #pragma unroll
                for (int i = 0; i < 2; ++i)
                    #pragma unroll
                    for (int j = 0; j < 4; ++j)
                        acc[i][j] = f32x4{0.f, 0.f, 0.f, 0.f};
            }
            short8 af[2][4];
            #pragma unroll
            for (int i = 0; i < 2; ++i)
                #pragma unroll
                for (int ks = 0; ks < 4; ++ks)
                    af[i][ks] = *(const short8*)&As[(wr * 32 + i * 16 + l15) * 130 + (ks * 4 + quad) * 8];
            #pragma unroll
            for (int ks = 0; ks < 4; ++ks)
                #pragma unroll
                for (int i = 0; i < 2; ++i)
                    #pragma unroll
                    for (int j = 0; j < 4; ++j)
                        acc[i][j] = MFMAH(af[i][ks], bfr[j][ks], acc[i][j]);

            if (KCH == 1) {
                // epilogue for this tile
                const int row0 = (blockIdx.x * TPB + t) * 64;
                #pragma unroll
                for (int i = 0; i < 2; ++i) {
                    #pragma unroll
                    for (int rr = 0; rr < 4; ++rr) {
                        size_t gr = (size_t)row0 + wr * 32 + i * 16 + quad * 4 + rr;
                        if (gr >= (size_t)n) continue;
                        #pragma unroll
                        for (int j = 0; j < 4; ++j) {
                            int col = wc * 64 + j * 16 + l15;
                            int gc  = bc + col;
                            float val = acc[i][j][rr];
                            if (MODE == 0) {
                                int sec = blockIdx.y;
                                const float* bp = (sec == 0) ? bias : (sec == 1 ? bias2 : bias3);
                                val += bp[col];
                                int idx = (sec == 0) ? col
                                        : (128 + ((col >> 1) << 2) + ((sec - 1) << 1) + (col & 1));
                                outb[gr * (size_t)QKVW + idx] = f2h(val);
                            } else if (MODE == 1) {
                                float* px = outf + gr * (size_t)outStride + gc;
                                *px = *px + val + bias[gc];
                            } else if (MODE == 2) {
                                val = gelu_fast(val + bias[gc]);
                                outb[gr * (size_t)outStride + gc] = f2h(val);
                            } else if (MODE == 3) {
                                val += bias[gc] + h2f(Rb[gr * (size_t)outStride + gc])
                                     + degs[gr] * wdeg[gc] + bdeg[gc];
                                outb[gr * (size_t)outStride + gc] = f2h(val);
                            }
                        }
                    }
                }
            }
            __syncthreads();                        // tile done: As/Bs safe to overwrite
        }
    }

    if (KCH > 1) {
        // full-K epilogue (TPB==1 path)
        const int row0 = blockIdx.x * TPB * 64;
        #pragma unroll
        for (int i = 0; i < 2; ++i) {
            #pragma unroll
            for (int rr = 0; rr < 4; ++rr) {
                size_t gr = (size_t)row0 + wr * 32 + i * 16 + quad * 4 + rr;
                if (gr >= (size_t)n) continue;
                #pragma unroll
                for (int j = 0; j < 4; ++j) {
                    int col = wc * 64 + j * 16 + l15;
                    int gc  = bc + col;
                    float val = acc[i][j][rr];
                    if (MODE == 1) {
                        float* px = outf + gr * (size_t)outStride + gc;
                        *px = *px + val + bias[gc];
                    }
                }
            }
        }
    }
}

// ---------------------------------------------------------------------------
// Degree pipeline
// ---------------------------------------------------------------------------
__global__ void deg_init(float* __restrict__ deg, int n)
{
    int i = blockIdx.x * 256 + threadIdx.x;
    if (i < n) deg[i] = 1.0f;     // self loop
}

__global__ void deg_count(const int* __restrict__ src, float* __restrict__ deg, int e)
{
    int i = blockIdx.x * 256 + threadIdx.x;
    if (i < e) atomicAdd(&deg[src[i]], 1.0f);
}

__global__ __launch_bounds__(256)
void deg_var(const float* __restrict__ deg, float* __restrict__ stats, float mean, int n)
{
    float acc = 0.f;
    for (int i = blockIdx.x * blockDim.x + threadIdx.x; i < n; i += gridDim.x * blockDim.x) {
        float d = deg[i] - mean;
        acc += d * d;
    }
    #pragma unroll
    for (int d = 1; d < 64; d <<= 1) acc += __shfl_xor(acc, d);
    __shared__ float wsum[4];
    int lane = threadIdx.x & 63, wv = threadIdx.x >> 6;
    if (lane == 0) wsum[wv] = acc;
    __syncthreads();
    if (threadIdx.x == 0) atomicAdd(stats, wsum[0] + wsum[1] + wsum[2] + wsum[3]);
}

__global__ void deg_norm(const float* __restrict__ deg, const float* __restrict__ stats,
                         float* __restrict__ degs, float mean, int n)
{
    int i = blockIdx.x * 256 + threadIdx.x;
    if (i >= n) return;
    float sd = sqrtf(stats[0] / (float)(n - 1));
    degs[i] = (deg[i] - mean) / (sd + 1e-6f);
}

// ---------------------------------------------------------------------------
// CSR build (grouped by dst; self loops appended)
// ---------------------------------------------------------------------------
__global__ void csr_count(const int* __restrict__ ei, int* __restrict__ counts, int e, int n)
{
    int i = blockIdx.x * 256 + threadIdx.x;
    if (i >= e + n) return;
    int d = (i < e) ? ei[e + i] : (i - e);
    atomicAdd(&counts[d], 1);
}

__global__ __launch_bounds__(256)
void scan_block(const int* __restrict__ in, int* __restrict__ out,
                int* __restrict__ sums, int n)
{
    __shared__ int buf[2][256];
    int t = threadIdx.x;
    int i = blockIdx.x * 256 + t;
    int v = (i < n) ? in[i] : 0;
    buf[0][t] = v;
    __syncthreads();
    int cur = 0;
    #pragma unroll
    for (int d = 1; d < 256; d <<= 1) {
        int val = buf[cur][t] + ((t >= d) ? buf[cur][t - d] : 0);
        buf[cur ^ 1][t] = val;
        cur ^= 1;
        __syncthreads();
    }
    if (i < n) out[i] = buf[cur][t] - v;   // exclusive
    if (t == 255 && sums) sums[blockIdx.x] = buf[cur][255];
}

__global__ void scan_add(int* __restrict__ offs, const int* __restrict__ carry, int n)
{
    int i = blockIdx.x * 256 + threadIdx.x;
    if (i < n) offs[i] += carry[blockIdx.x];
}

__global__ void csr_fill(const int* __restrict__ ei, const int* __restrict__ offs,
                         int* __restrict__ cursor, int* __restrict__ csr_src, int e, int n)
{
    int i = blockIdx.x * 256 + threadIdx.x;
    if (i >= e + n) return;
    int d, s;
    if (i < e) { s = ei[i]; d = ei[e + i]; }
    else       { s = d = i - e; }
    int pos = offs[d] + atomicAdd(&cursor[d], 1);
    csr_src[pos] = s;
}

// ---------------------------------------------------------------------------
// Attention: one wave per dst node, online softmax, 2-edge unroll with
// 2-deep prefetch. Lane l holds dims {2l, 2l+1}; head = lane>>3.
// qkv rows fp16: [q(128) | k0,k1,v0,v1 interleaved (256)]. aggr out fp16.
// ---------------------------------------------------------------------------
__global__ __launch_bounds__(256)
void attn_kernel(const unsigned short* __restrict__ qkv,
                 const int* __restrict__ csr_src, const int* __restrict__ offs,
                 const int* __restrict__ counts,
                 unsigned short* __restrict__ aggr, int n)
{
    int wave = threadIdx.x >> 6;
    int lane = threadIdx.x & 63;
    int node = blockIdx.x * 4 + wave;
    if (node >= n) return;

    ushort2 qu = *(const ushort2*)(qkv + (size_t)node * QKVW + lane * 2);
    float qx = h2f(qu.x), qy = h2f(qu.y);
    int beg = offs[node], cnt = counts[node];

    float m = -1e30f, s = 0.f, ax = 0.f, ay = 0.f;
    ushort4 kvA = {0,0,0,0}, kvB = {0,0,0,0};
    if (cnt > 1) {
        int j0 = csr_src[beg], j1 = csr_src[beg + 1];
        kvA = *(const ushort4*)(qkv + (size_t)j0 * QKVW + DMODEL + lane * 4);
        kvB = *(const ushort4*)(qkv + (size_t)j1 * QKVW + DMODEL + lane * 4);
    } else {
        int j0 = csr_src[beg];
        kvA = *(const ushort4*)(qkv + (size_t)j0 * QKVW + DMODEL + lane * 4);
    }
    int t = 0;
    for (; t + 1 < cnt; t += 2) {
        ushort4 k0 = kvA, k1 = kvB;
        int rem = cnt - t - 2;
        if (rem >= 2) {
            int j0 = csr_src[beg + t + 2], j1 = csr_src[beg + t + 3];
            kvA = *(const ushort4*)(qkv + (size_t)j0 * QKVW + DMODEL + lane * 4);
            kvB = *(const ushort4*)(qkv + (size_t)j1 * QKVW + DMODEL + lane * 4);
        } else if (rem == 1) {
            int j0 = csr_src[beg + t + 2];
            kvA = *(const ushort4*)(qkv + (size_t)j0 * QKVW + DMODEL + lane * 4);
        }
        float p0 = qx * h2f(k0.x) + qy * h2f(k0.y);
        float p1 = qx * h2f(k1.x) + qy * h2f(k1.y);
        p0 += __shfl_xor(p0, 1); p1 += __shfl_xor(p1, 1);
        p0 += __shfl_xor(p0, 2); p1 += __shfl_xor(p1, 2);
        p0 += __shfl_xor(p0, 4); p1 += __shfl_xor(p1, 4);
        p0 *= 0.25f; p1 *= 0.25f;
        p0 = (p0 != p0) ? 0.f : fminf(fmaxf(p0, -50.f), 50.f);
        p1 = (p1 != p1) ? 0.f : fminf(fmaxf(p1, -50.f), 50.f);
        float nm = fmaxf(m, fmaxf(p0, p1));
        float sc = __expf(m - nm);
        float e0 = __expf(p0 - nm), e1 = __expf(p1 - nm);
        s  = s  * sc + e0 + e1;
        ax = ax * sc + e0 * h2f(k0.z) + e1 * h2f(k1.z);
        ay = ay * sc + e0 * h2f(k0.w) + e1 * h2f(k1.w);
        m = nm;
    }
    if (t < cnt) {
        float p0 = qx * h2f(kvA.x) + qy * h2f(kvA.y);
        p0 += __shfl_xor(p0, 1); p0 += __shfl_xor(p0, 2); p0 += __shfl_xor(p0, 4);
        p0 *= 0.25f;
        p0 = (p0 != p0) ? 0.f : fminf(fmaxf(p0, -50.f), 50.f);
        float nm = fmaxf(m, p0);
        float sc = __expf(m - nm), e0 = __expf(p0 - nm);
        s = s * sc + e0;
        ax = ax * sc + e0 * h2f(kvA.z);
        ay = ay * sc + e0 * h2f(kvA.w);
        m = nm;
    }
    float r = 1.0f / (s + 1e-16f);
    ushort2 o;
    o.x = f2h(ax * r);
    o.y = f2h(ay * r);
    *(ushort2*)(aggr + (size_t)node * DMODEL + lane * 2) = o;
}

// ---------------------------------------------------------------------------
extern "C" void kernel_launch(void* const* d_in, const int* in_sizes, int n_in,
                              void* d_out, int out_size, void* d_ws, size_t ws_size,
                              hipStream_t stream)
{
    const float* x_in  = (const float*)d_in[0];
    const int*   ei    = (const int*)d_in[1];
    const float* Wq    = (const float*)d_in[2];
    const float* Wk    = (const float*)d_in[3];
    const float* Wv    = (const float*)d_in[4];
    const float* Wo    = (const float*)d_in[5];
    const float* Wpos  = (const float*)d_in[6];
    const float* Wdeg  = (const float*)d_in[7];
    const float* W1    = (const float*)d_in[8];
    const float* W2    = (const float*)d_in[9];
    const float* bq    = (const float*)d_in[10];
    const float* bk    = (const float*)d_in[11];
    const float* bv    = (const float*)d_in[12];
    const float* bo    = (const float*)d_in[13];
    const float* bpos  = (const float*)d_in[14];
    const float* bdeg  = (const float*)d_in[15];
    const float* ln1_b = (const float*)d_in[16];
    const float* ln2_b = (const float*)d_in[17];
    const float* b1    = (const float*)d_in[18];
    const float* b2    = (const float*)d_in[19];
    const float* ln1_g = (const float*)d_in[20];
    const float* ln2_g = (const float*)d_in[21];

    const int n   = in_sizes[0] / DMODEL;   // 50000
    const int e   = in_sizes[1] / 2;        // 500000
    const int tot = e + n;

    float* x = (float*)d_out;               // running node features (fp32)

    // ---- workspace layout (256B-aligned slices) ----
    char* p = (char*)d_ws;
    auto alloc = [&](size_t bytes) -> void* {
        void* r = (void*)p;
        p += (bytes + 255) & ~(size_t)255;
        return r;
    };
    float* deg     = (float*)alloc((size_t)n * 4);
    float* degs    = (float*)alloc((size_t)n * 4);
    float* stats   = (float*)alloc(256);
    int*   counts  = (int*)alloc((size_t)n * 4);
    int*   offs    = (int*)alloc((size_t)n * 4);
    int*   cursor  = (int*)alloc((size_t)n * 4);
    int*   bsums   = (int*)alloc(1024);
    int*   carry   = (int*)alloc(1024);
    int*   csr_src = (int*)alloc((size_t)tot * 4);
    unsigned short* xnb  = (unsigned short*)alloc((size_t)MPAD * DMODEL * 2);
    unsigned short* xp   = (unsigned short*)alloc((size_t)MPAD * DMODEL * 2);
    unsigned short* aggr = (unsigned short*)alloc((size_t)MPAD * DMODEL * 2);
    unsigned short* qkv  = (unsigned short*)alloc((size_t)MPAD * QKVW * 2);   // fp16
    unsigned short* hb   = (unsigned short*)alloc((size_t)MPAD * FFDIM * 2);
    unsigned short* wqkvt = (unsigned short*)alloc((size_t)NLAYER * QKVW * DMODEL * 2);
    unsigned short* wot  = (unsigned short*)alloc((size_t)NLAYER * DMODEL * DMODEL * 2);
    unsigned short* wpt  = (unsigned short*)alloc((size_t)NLAYER * DMODEL * DMODEL * 2);
    unsigned short* w1t  = (unsigned short*)alloc((size_t)NLAYER * DMODEL * FFDIM * 2);
    unsigned short* w2t  = (unsigned short*)alloc((size_t)NLAYER * FFDIM * DMODEL * 2);

    const int nb_n = (n + 255) / 256;
    const int nb_e = (e + 255) / 256;
    const int nb_t = (tot + 255) / 256;
    const int nscan = nb_n;

    // ---- init ----
    hipMemcpyAsync(x, x_in, (size_t)n * DMODEL * 4, hipMemcpyDeviceToDevice, stream);
    hipMemsetAsync(stats, 0, 256, stream);
    hipMemsetAsync(counts, 0, (size_t)n * 4, stream);
    hipMemsetAsync(cursor, 0, (size_t)n * 4, stream);

    // ---- weight convert+transpose (fp16 [NR][K]); Wq/Wk/Wv concat to [384][128]
    {
        int tDD = NLAYER * DMODEL * DMODEL;
        int tW1 = NLAYER * DMODEL * FFDIM;
        wconv<<<(tDD + 255) / 256, 256, 0, stream>>>(Wq,   wqkvt, DMODEL, DMODEL, tDD, QKVW, 0);
        wconv<<<(tDD + 255) / 256, 256, 0, stream>>>(Wk,   wqkvt, DMODEL, DMODEL, tDD, QKVW, 128);
        wconv<<<(tDD + 255) / 256, 256, 0, stream>>>(Wv,   wqkvt, DMODEL, DMODEL, tDD, QKVW, 256);
        wconv<<<(tDD + 255) / 256, 256, 0, stream>>>(Wo,   wot, DMODEL, DMODEL, tDD, DMODEL, 0);
        wconv<<<(tDD + 255) / 256, 256, 0, stream>>>(Wpos, wpt, DMODEL, DMODEL, tDD, DMODEL, 0);
        wconv<<<(tW1 + 255) / 256, 256, 0, stream>>>(W1,   w1t, DMODEL, FFDIM,  tW1, FFDIM, 0);
        wconv<<<(tW1 + 255) / 256, 256, 0, stream>>>(W2,   w2t, FFDIM,  DMODEL, tW1, DMODEL, 0);
    }

    // ---- degree (layer-invariant) ----
    const float mean = (float)((double)tot / (double)n);
    deg_init<<<nb_n, 256, 0, stream>>>(deg, n);
    deg_count<<<nb_e, 256, 0, stream>>>(ei, deg, e);
    deg_var<<<196, 256, 0, stream>>>(deg, stats, mean, n);
    deg_norm<<<nb_n, 256, 0, stream>>>(deg, stats, degs, mean, n);

    // ---- CSR by dst (layer-invariant) ----
    csr_count<<<nb_t, 256, 0, stream>>>(ei, counts, e, n);
    scan_block<<<nscan, 256, 0, stream>>>(counts, offs, bsums, n);
    scan_block<<<1, 256, 0, stream>>>(bsums, carry, nullptr, nscan);
    scan_add<<<nscan, 256, 0, stream>>>(offs, carry, n);
    csr_fill<<<nb_t, 256, 0, stream>>>(ei, offs, cursor, csr_src, e, n);

    const int nTiles  = MPAD / 64;           // 782
    const int gx2     = nTiles / 2;          // 391 (TPB=2)
    const int ln_grid = (n + 3) / 4;

    for (int l = 0; l < NLAYER; ++l) {
        const size_t DD = (size_t)DMODEL * DMODEL;
        const float* wdeg = Wdeg + (size_t)l * DMODEL;
        const unsigned short* wqkv = wqkvt + (size_t)l * QKVW * DMODEL;
        const unsigned short* wo   = wot + l * DD;
        const unsigned short* wpos = wpt + l * DD;
        const unsigned short* w1   = w1t + (size_t)l * DMODEL * FFDIM;
        const unsigned short* w2   = w2t + (size_t)l * FFDIM * DMODEL;

        // pre-attention LN -> fp16
        ln_kernel<<<ln_grid, 256, 0, stream>>>(x, ln1_g + l * DMODEL, ln1_b + l * DMODEL, xnb, n);
        // xp = xn + xn@Wpos + bpos + degs*wdeg + bdeg   (fp16 out)
        gemm_bres<3, 1, 2><<<dim3(gx2, 1), 256, 0, stream>>>(
            xnb, DMODEL, wpos, DMODEL,
            bpos + l * DMODEL, nullptr, nullptr,
            xnb, degs, wdeg, bdeg + l * DMODEL,
            nullptr, xp, DMODEL, n);
        // fused QKV -> fp16 qkv buffer (q | interleaved kv)
        gemm_bres<0, 1, 2><<<dim3(gx2, 3), 256, 0, stream>>>(
            xp, DMODEL, wqkv, DMODEL,
            bq + l * DMODEL, bk + l * DMODEL, bv + l * DMODEL,
            nullptr, nullptr, nullptr, nullptr,
            nullptr, qkv, QKVW, n);
        // attention -> aggr (fp16)
        attn_kernel<<<ln_grid, 256, 0, stream>>>(qkv, csr_src, offs, counts, aggr, n);
        // x = x + aggr@Wo + bo   (fp32, read-modify-write)
        gemm_bres<1, 1, 2><<<dim3(gx2, 1), 256, 0, stream>>>(
            aggr, DMODEL, wo, DMODEL,
            bo + l * DMODEL, nullptr, nullptr,
            nullptr, nullptr, nullptr, nullptr,
            x, nullptr, DMODEL, n);
        // FFN
        ln_kernel<<<ln_grid, 256, 0, stream>>>(x, ln2_g + l * DMODEL, ln2_b + l * DMODEL, xnb, n);
        gemm_bres<2, 1, 2><<<dim3(gx2, 4), 256, 0, stream>>>(
            xnb, DMODEL, w1, DMODEL,
            b1 + l * FFDIM, nullptr, nullptr,
            nullptr, nullptr, nullptr, nullptr,
            nullptr, hb, FFDIM, n);
        gemm_bres<1, 4, 1><<<dim3(nTiles, 1), 256, 0, stream>>>(
            hb, FFDIM, w2, FFDIM,
            b2 + l * DMODEL, nullptr, nullptr,
            nullptr, nullptr, nullptr, nullptr,
            x, nullptr, DMODEL, n);
    }
}